// Round 4
// baseline (1139.300 us; speedup 1.0000x reference)
//
#include <hip/hip_runtime.h>

typedef unsigned short u16;
typedef short bf16x8 __attribute__((ext_vector_type(8)));
typedef float f32x4 __attribute__((ext_vector_type(4)));

__device__ __forceinline__ u16 f2b(float f) {
  union { float f; unsigned u; } v; v.f = f;
  unsigned r = v.u + 0x7FFFu + ((v.u >> 16) & 1u);
  return (u16)(r >> 16);
}
__device__ __forceinline__ float b2f(u16 h) {
  union { unsigned u; float f; } v; v.u = ((unsigned)h) << 16;
  return v.f;
}

// ---- LDS staging: R x K bf16 tile, XOR-swizzled (byte ^= (row&7)<<4) so MFMA
// fragment ds_read_b128 at row-stride 2K (384B/512B ≡ bank 0) lands ~2-way (free).
template <int R, int K, int T>
__device__ __forceinline__ void stage_f32(const float* __restrict__ src, int rowStride,
                                          char* lds, int tid) {
  constexpr int CPR = K / 4;
  constexpr int CHUNKS = R * CPR;
  #pragma unroll
  for (int ci = tid; ci < CHUNKS; ci += T) {
    int r = ci / CPR, u = ci % CPR;
    float4 vv = *reinterpret_cast<const float4*>(src + (size_t)r * rowStride + u * 4);
    ushort4 h;
    h.x = f2b(vv.x); h.y = f2b(vv.y); h.z = f2b(vv.z); h.w = f2b(vv.w);
    int bc = (u * 8) ^ ((r & 7) << 4);
    *reinterpret_cast<ushort4*>(lds + r * (2 * K) + bc) = h;
  }
}

template <int R, int K, int T>
__device__ __forceinline__ void stage_b16(const u16* __restrict__ src, int rowStride,
                                          char* lds, int tid) {
  constexpr int CPR = K / 8;
  constexpr int CHUNKS = R * CPR;
  #pragma unroll
  for (int ci = tid; ci < CHUNKS; ci += T) {
    int r = ci / CPR, u = ci % CPR;
    int4 vv = *reinterpret_cast<const int4*>(src + (size_t)r * rowStride + u * 8);
    int bc = (u * 16) ^ ((r & 7) << 4);
    *reinterpret_cast<int4*>(lds + r * (2 * K) + bc) = vv;
  }
}

// ---- MFMA over one staged K-chunk. A [BM][KC], B [BN][KC], row-major bf16
// ([m][k]/[n][k]), XOR swizzle as above. Accumulates into acc[i][jo+j]. jo MUST be a
// compile-time constant at every call site (rule #20: runtime-indexed regs -> scratch).
template <int KC, int FM, int FN, int FNT>
__device__ __forceinline__ void mma_chunk(const char* ldsA, const char* ldsB, int lane,
                                          int wm0, int wn0, int jo, f32x4 (&acc)[FM][FNT]) {
  constexpr int LD = 2 * KC;
  #pragma unroll
  for (int ks = 0; ks < KC / 32; ++ks) {
    bf16x8 a[FM], b[FN];
    int kb = ks * 64 + ((lane >> 4) << 4);
    #pragma unroll
    for (int i = 0; i < FM; ++i) {
      int row = wm0 + i * 16 + (lane & 15);
      a[i] = *reinterpret_cast<const bf16x8*>(ldsA + row * LD + (kb ^ ((row & 7) << 4)));
    }
    #pragma unroll
    for (int j = 0; j < FN; ++j) {
      int row = wn0 + j * 16 + (lane & 15);
      b[j] = *reinterpret_cast<const bf16x8*>(ldsB + row * LD + (kb ^ ((row & 7) << 4)));
    }
    #pragma unroll
    for (int i = 0; i < FM; ++i)
      #pragma unroll
      for (int j = 0; j < FN; ++j)
        acc[i][jo + j] =
            __builtin_amdgcn_mfma_f32_16x16x32_bf16(a[i], b[j], acc[i][jo + j], 0, 0, 0);
  }
}

// ---- K1: qkv = x @ w_qkv^T + b_qkv. x-tile staged ONCE; 9 weight chunks looped
// in-block. Natural row j -> window row w(j) scatter on store. q/k/v bf16 window-major.
__global__ __launch_bounds__(256) void k_qkv(const float* __restrict__ x,
                                             const float* __restrict__ wqkv,
                                             const float* __restrict__ bqkv,
                                             u16* __restrict__ q, u16* __restrict__ kk,
                                             u16* __restrict__ v) {
  __shared__ __align__(16) char ldsA[128 * 384];
  __shared__ __align__(16) char ldsB[64 * 384];
  int tid = threadIdx.x;
  stage_f32<128, 192, 256>(x + (size_t)blockIdx.x * (128 * 192), 192, ldsA, tid);
  int lane = tid & 63, wid = tid >> 6;
  int wm0 = wid * 32;
  int colL = lane & 15, rq = (lane >> 4) * 4;
  #pragma unroll 1
  for (int ch = 0; ch < 9; ++ch) {
    if (ch) __syncthreads();
    stage_f32<64, 192, 256>(wqkv + ch * (64 * 192), 192, ldsB, tid);
    __syncthreads();
    f32x4 acc[2][4];
    #pragma unroll
    for (int i = 0; i < 2; ++i)
      #pragma unroll
      for (int j = 0; j < 4; ++j)
        #pragma unroll
        for (int e = 0; e < 4; ++e) acc[i][j][e] = 0.f;
    mma_chunk<192, 2, 4, 4>(ldsA, ldsB, lane, wm0, 0, 0, acc);
    u16* dst;
    int pbase = ch * 64;
    if (ch < 3) dst = q;
    else if (ch < 6) { dst = kk; pbase -= 192; }
    else { dst = v; pbase -= 384; }
    #pragma unroll
    for (int j = 0; j < 4; ++j) {
      int pc = pbase + j * 16 + colL;
      float bias = bqkv[ch * 64 + j * 16 + colL];
      #pragma unroll
      for (int i = 0; i < 2; ++i)
        #pragma unroll
        for (int rr = 0; rr < 4; ++rr) {
          int m = blockIdx.x * 128 + wm0 + i * 16 + rq + rr;  // natural row j
          int b = m >> 16, i1 = (m >> 12) & 15, i2 = (m >> 8) & 15, i3 = (m >> 4) & 15,
              i4 = m & 15;
          int w = (((((b << 4) | i1) << 4) | i3) << 8) | (i2 << 4) | i4;
          dst[(size_t)w * 192 + pc] = f2b(acc[i][j][rr] + bias);
        }
    }
  }
}

// ---- K2: fully fused per-window attention: QK^T -> softmax -> P(LDS) -> PV -> o.
// One block = one window (512 thr, 8 waves). LDS phases: {Q 96K | K 48K} then
// {P 128K | Vchunk 16K}. P never touches HBM; V transposed in-LDS from natural v.
__global__ __launch_bounds__(512) void k_fused(const u16* __restrict__ q,
                                               const u16* __restrict__ kk,
                                               const u16* __restrict__ v,
                                               u16* __restrict__ o) {
  __shared__ __align__(16) char lds[147456];
  char* ldsQ = lds;            // [0, 96K)   phase A
  char* ldsK = lds + 98304;    // [96K,144K) phase A
  char* ldsP = lds;            // [0,128K)   phase B (reuses Q/K space)
  char* ldsV = lds + 131072;   // [128K,144K) phase B, 32 c-rows x 512B
  int tid = threadIdx.x, z = blockIdx.x;
  int lane = tid & 63, wid = tid >> 6;
  int wm0 = wid * 32;
  const u16* qb = q + (size_t)z * 49152;
  const u16* kb = kk + (size_t)z * 49152;
  const u16* vb = v + (size_t)z * 49152;
  u16* ob = o + (size_t)z * 49152;

  stage_b16<256, 192, 512>(qb, 192, ldsQ, tid);
  stage_b16<128, 192, 512>(kb, 192, ldsK, tid);
  // reg-prefetch K rows 128..255 (flies during first QK^T half)
  int4 kreg[6];
  #pragma unroll
  for (int s = 0; s < 6; ++s) {
    int ci = tid + s * 512;
    int r = ci / 24, u = ci % 24;
    kreg[s] = *reinterpret_cast<const int4*>(kb + (size_t)(128 + r) * 192 + u * 8);
  }
  f32x4 acc[2][16];
  #pragma unroll
  for (int i = 0; i < 2; ++i)
    #pragma unroll
    for (int j = 0; j < 16; ++j)
      #pragma unroll
      for (int e = 0; e < 4; ++e) acc[i][j][e] = 0.f;
  __syncthreads();
  mma_chunk<192, 2, 8, 16>(ldsQ, ldsK, lane, wm0, 0, 0, acc);
  __syncthreads();
  #pragma unroll
  for (int s = 0; s < 6; ++s) {
    int ci = tid + s * 512;
    int r = ci / 24, u = ci % 24;
    *reinterpret_cast<int4*>(ldsK + r * 384 + ((u * 16) ^ ((r & 7) << 4))) = kreg[s];
  }
  __syncthreads();
  mma_chunk<192, 2, 8, 16>(ldsQ, ldsK, lane, wm0, 0, 8, acc);
  __syncthreads();  // all QK^T LDS reads done; Q/K space now reusable

  // prefetch V chunk 0 (flies during softmax + P writes)
  int4 vreg[2];
  #pragma unroll
  for (int s = 0; s < 2; ++s) {
    int ci = tid + s * 512;
    int tt = ci >> 2, u = ci & 3;
    vreg[s] = *reinterpret_cast<const int4*>(vb + (size_t)tt * 192 + u * 8);
  }

  // in-register row softmax; write bf16 P to LDS (each wave only its own 32 rows,
  // which only it reads back as PV A-fragments -> no cross-wave sync needed)
  const float scale = 0.07216878364870323f;  // 1/sqrt(192)
  int colL = lane & 15, rq = (lane >> 4) * 4;
  #pragma unroll
  for (int i = 0; i < 2; ++i)
    #pragma unroll
    for (int rr = 0; rr < 4; ++rr) {
      float m = -1e30f;
      #pragma unroll
      for (int j = 0; j < 16; ++j) m = fmaxf(m, acc[i][j][rr]);
      #pragma unroll
      for (int off = 8; off; off >>= 1) m = fmaxf(m, __shfl_xor(m, off));
      float s = 0.f;
      #pragma unroll
      for (int j = 0; j < 16; ++j) {
        float e = __expf((acc[i][j][rr] - m) * scale);
        acc[i][j][rr] = e;
        s += e;
      }
      #pragma unroll
      for (int off = 8; off; off >>= 1) s += __shfl_xor(s, off);
      float iv = 1.0f / s;
      int row = wm0 + i * 16 + rq + rr;
      int swz = (row & 7) << 4;
      #pragma unroll
      for (int j = 0; j < 16; ++j) {
        int tc = j * 16 + colL;
        *reinterpret_cast<u16*>(ldsP + row * 512 + ((tc * 2) ^ swz)) =
            f2b(acc[i][j][rr] * iv);
      }
    }

  // PV: 6 chunks of 32 channels; V transposed into LDS; next chunk's global loads
  // issued before this chunk's MFMA (software pipeline)
  #pragma unroll 1
  for (int cc = 0; cc < 6; ++cc) {
    __syncthreads();  // prior chunk's ldsV reads (and, at cc=0, QK^T reads) done
    #pragma unroll
    for (int s = 0; s < 2; ++s) {
      int ci = tid + s * 512;
      int tt = ci >> 2, u = ci & 3;
      unsigned w0 = (unsigned)vreg[s].x, w1 = (unsigned)vreg[s].y,
               w2 = (unsigned)vreg[s].z, w3 = (unsigned)vreg[s].w;
      int tb = tt * 2;
      char* base = ldsV + u * 8 * 512;
      *reinterpret_cast<u16*>(base + 0 * 512 + (tb ^ 0x00)) = (u16)(w0 & 0xFFFF);
      *reinterpret_cast<u16*>(base + 1 * 512 + (tb ^ 0x10)) = (u16)(w0 >> 16);
      *reinterpret_cast<u16*>(base + 2 * 512 + (tb ^ 0x20)) = (u16)(w1 & 0xFFFF);
      *reinterpret_cast<u16*>(base + 3 * 512 + (tb ^ 0x30)) = (u16)(w1 >> 16);
      *reinterpret_cast<u16*>(base + 4 * 512 + (tb ^ 0x40)) = (u16)(w2 & 0xFFFF);
      *reinterpret_cast<u16*>(base + 5 * 512 + (tb ^ 0x50)) = (u16)(w2 >> 16);
      *reinterpret_cast<u16*>(base + 6 * 512 + (tb ^ 0x60)) = (u16)(w3 & 0xFFFF);
      *reinterpret_cast<u16*>(base + 7 * 512 + (tb ^ 0x70)) = (u16)(w3 >> 16);
    }
    if (cc < 5) {
      #pragma unroll
      for (int s = 0; s < 2; ++s) {
        int ci = tid + s * 512;
        int tt = ci >> 2, u = ci & 3;
        vreg[s] =
            *reinterpret_cast<const int4*>(vb + (size_t)tt * 192 + (cc + 1) * 32 + u * 8);
      }
    }
    __syncthreads();
    f32x4 acc2[2][2];
    #pragma unroll
    for (int i = 0; i < 2; ++i)
      #pragma unroll
      for (int j = 0; j < 2; ++j)
        #pragma unroll
        for (int e = 0; e < 4; ++e) acc2[i][j][e] = 0.f;
    mma_chunk<256, 2, 2, 2>(ldsP, ldsV, lane, wm0, 0, 0, acc2);
    #pragma unroll
    for (int i = 0; i < 2; ++i)
      #pragma unroll
      for (int j = 0; j < 2; ++j)
        #pragma unroll
        for (int rr = 0; rr < 4; ++rr) {
          int row = wm0 + i * 16 + rq + rr;
          ob[row * 192 + cc * 32 + j * 16 + colL] = f2b(acc2[i][j][rr]);
        }
  }
}

// ---- K3: lepe (depthwise 3x3 SAME on the reinterpreted [C][16][16] view) added to o.
__global__ __launch_bounds__(256) void k_lepe(const u16* __restrict__ v,
                                              u16* __restrict__ o,
                                              const float* __restrict__ wpe,
                                              const float* __restrict__ bpe) {
  unsigned idx = blockIdx.x * 256u + threadIdx.x;  // over 1024*49152
  unsigned n = idx / 49152u, f = idx % 49152u;
  int cp = f >> 8, rem = f & 255, y = rem >> 4, xx = rem & 15;
  const float* wp = wpe + cp * 9;
  float a = bpe[cp];
  const u16* vb = v + (size_t)n * 49152 + cp * 256;
  #pragma unroll
  for (int dy = -1; dy <= 1; ++dy) {
    int yy = y + dy;
    if ((unsigned)yy < 16u) {
      #pragma unroll
      for (int dx = -1; dx <= 1; ++dx) {
        int xn = xx + dx;
        if ((unsigned)xn < 16u) a += wp[(dy + 1) * 3 + (dx + 1)] * b2f(vb[yy * 16 + xn]);
      }
    }
  }
  o[idx] = f2b(b2f(o[idx]) + a);
}

// ---- K4: out = (o @ w_out^T + b_out); o-tile staged ONCE, 3 weight chunks in-block;
// window row w -> natural row j scatter on the f32 store.
__global__ __launch_bounds__(256) void k_outproj(const u16* __restrict__ o,
                                                 const float* __restrict__ wout,
                                                 const float* __restrict__ bout,
                                                 float* __restrict__ out) {
  __shared__ __align__(16) char ldsA[128 * 384];
  __shared__ __align__(16) char ldsB[64 * 384];
  int tid = threadIdx.x;
  stage_b16<128, 192, 256>(o + (size_t)blockIdx.x * (128 * 192), 192, ldsA, tid);
  int lane = tid & 63, wid = tid >> 6;
  int wm0 = wid * 32;
  int colL = lane & 15, rq = (lane >> 4) * 4;
  #pragma unroll 1
  for (int ch = 0; ch < 3; ++ch) {
    if (ch) __syncthreads();
    stage_f32<64, 192, 256>(wout + ch * (64 * 192), 192, ldsB, tid);
    __syncthreads();
    f32x4 acc[2][4];
    #pragma unroll
    for (int i = 0; i < 2; ++i)
      #pragma unroll
      for (int j = 0; j < 4; ++j)
        #pragma unroll
        for (int e = 0; e < 4; ++e) acc[i][j][e] = 0.f;
    mma_chunk<192, 2, 4, 4>(ldsA, ldsB, lane, wm0, 0, 0, acc);
    #pragma unroll
    for (int j = 0; j < 4; ++j) {
      int p = ch * 64 + j * 16 + colL;
      float bias = bout[p];
      #pragma unroll
      for (int i = 0; i < 2; ++i)
        #pragma unroll
        for (int rr = 0; rr < 4; ++rr) {
          int w = blockIdx.x * 128 + wm0 + i * 16 + rq + rr;
          int n = w >> 8, t = w & 255;
          int b = n >> 8, i1 = (n >> 4) & 15, i3 = n & 15, i2 = t >> 4, i4 = t & 15;
          int jj = (((((((b << 4) | i1) << 4) | i2) << 4) | i3) << 4) | i4;
          out[(size_t)jj * 192 + p] = acc[i][j][rr] + bias;
        }
    }
  }
}

extern "C" void kernel_launch(void* const* d_in, const int* in_sizes, int n_in,
                              void* d_out, int out_size, void* d_ws, size_t ws_size,
                              hipStream_t stream) {
  const float* x = (const float*)d_in[0];
  const float* w_qkv = (const float*)d_in[1];
  const float* b_qkv = (const float*)d_in[2];
  const float* w_pe = (const float*)d_in[3];
  const float* b_pe = (const float*)d_in[4];
  const float* w_out = (const float*)d_in[5];
  const float* b_out = (const float*)d_in[6];
  float* out = (float*)d_out;
  char* ws = (char*)d_ws;

  // Workspace (peak 403MB):
  //   q [0,100M) k [100M,201M) v [201M,302M) o [302M,403M)
  //   (o cannot alias q/k/v: k_fused writes o while other blocks still read q/k/v)
  u16* q = (u16*)(ws + 0);
  u16* k = (u16*)(ws + 100663296);
  u16* v = (u16*)(ws + 201326592);
  u16* o = (u16*)(ws + 301989888);

  k_qkv<<<dim3(2048), 256, 0, stream>>>(x, w_qkv, b_qkv, q, k, v);
  k_fused<<<dim3(1024), 512, 0, stream>>>(q, k, v, o);
  k_lepe<<<dim3(196608), 256, 0, stream>>>(v, o, w_pe, b_pe);
  k_outproj<<<dim3(2048), 256, 0, stream>>>(o, w_out, b_out, out);
}

// Round 5
// 862.228 us; speedup vs baseline: 1.3213x; 1.3213x over previous
//
#include <hip/hip_runtime.h>

typedef unsigned short u16;
typedef short bf16x8 __attribute__((ext_vector_type(8)));
typedef float f32x4 __attribute__((ext_vector_type(4)));

__device__ __forceinline__ u16 f2b(float f) {
  union { float f; unsigned u; } v; v.f = f;
  unsigned r = v.u + 0x7FFFu + ((v.u >> 16) & 1u);
  return (u16)(r >> 16);
}
__device__ __forceinline__ float b2f(u16 h) {
  union { unsigned u; float f; } v; v.u = ((unsigned)h) << 16;
  return v.f;
}

// ---- LDS staging: R x K bf16 tile, XOR-swizzled (byte ^= (row&7)<<4) so MFMA
// fragment ds_read_b128 at row-stride 2K (384B/512B ≡ bank 0) lands ~2-way (free).
template <int R, int K, int T>
__device__ __forceinline__ void stage_f32(const float* __restrict__ src, int rowStride,
                                          char* lds, int tid) {
  constexpr int CPR = K / 4;
  constexpr int CHUNKS = R * CPR;
  #pragma unroll
  for (int ci = tid; ci < CHUNKS; ci += T) {
    int r = ci / CPR, u = ci % CPR;
    float4 vv = *reinterpret_cast<const float4*>(src + (size_t)r * rowStride + u * 4);
    ushort4 h;
    h.x = f2b(vv.x); h.y = f2b(vv.y); h.z = f2b(vv.z); h.w = f2b(vv.w);
    int bc = (u * 8) ^ ((r & 7) << 4);
    *reinterpret_cast<ushort4*>(lds + r * (2 * K) + bc) = h;
  }
}

template <int R, int K, int T>
__device__ __forceinline__ void stage_b16(const u16* __restrict__ src, int rowStride,
                                          char* lds, int tid) {
  constexpr int CPR = K / 8;
  constexpr int CHUNKS = R * CPR;
  #pragma unroll
  for (int ci = tid; ci < CHUNKS; ci += T) {
    int r = ci / CPR, u = ci % CPR;
    int4 vv = *reinterpret_cast<const int4*>(src + (size_t)r * rowStride + u * 8);
    int bc = (u * 16) ^ ((r & 7) << 4);
    *reinterpret_cast<int4*>(lds + r * (2 * K) + bc) = vv;
  }
}

// ---- MFMA over one staged K-chunk. A [BM][KC], B [BN][KC], row-major bf16
// ([m][k]/[n][k]), XOR swizzle as above. Accumulates into acc[i][jo+j]. jo MUST be a
// compile-time constant at every call site (rule #20: runtime-indexed regs -> scratch).
template <int KC, int FM, int FN, int FNT>
__device__ __forceinline__ void mma_chunk(const char* ldsA, const char* ldsB, int lane,
                                          int wm0, int wn0, int jo, f32x4 (&acc)[FM][FNT]) {
  constexpr int LD = 2 * KC;
  #pragma unroll
  for (int ks = 0; ks < KC / 32; ++ks) {
    bf16x8 a[FM], b[FN];
    int kb = ks * 64 + ((lane >> 4) << 4);
    #pragma unroll
    for (int i = 0; i < FM; ++i) {
      int row = wm0 + i * 16 + (lane & 15);
      a[i] = *reinterpret_cast<const bf16x8*>(ldsA + row * LD + (kb ^ ((row & 7) << 4)));
    }
    #pragma unroll
    for (int j = 0; j < FN; ++j) {
      int row = wn0 + j * 16 + (lane & 15);
      b[j] = *reinterpret_cast<const bf16x8*>(ldsB + row * LD + (kb ^ ((row & 7) << 4)));
    }
    #pragma unroll
    for (int i = 0; i < FM; ++i)
      #pragma unroll
      for (int j = 0; j < FN; ++j)
        acc[i][jo + j] =
            __builtin_amdgcn_mfma_f32_16x16x32_bf16(a[i], b[j], acc[i][jo + j], 0, 0, 0);
  }
}

// ---- K1: qkv = x @ w_qkv^T + b_qkv. x-tile staged ONCE; 9 weight chunks looped
// in-block. Natural row j -> window row w(j) scatter on store. q/k/v bf16 window-major.
__global__ __launch_bounds__(256) void k_qkv(const float* __restrict__ x,
                                             const float* __restrict__ wqkv,
                                             const float* __restrict__ bqkv,
                                             u16* __restrict__ q, u16* __restrict__ kk,
                                             u16* __restrict__ v) {
  __shared__ __align__(16) char ldsA[128 * 384];
  __shared__ __align__(16) char ldsB[64 * 384];
  int tid = threadIdx.x;
  stage_f32<128, 192, 256>(x + (size_t)blockIdx.x * (128 * 192), 192, ldsA, tid);
  int lane = tid & 63, wid = tid >> 6;
  int wm0 = wid * 32;
  int colL = lane & 15, rq = (lane >> 4) * 4;
  #pragma unroll 1
  for (int ch = 0; ch < 9; ++ch) {
    if (ch) __syncthreads();
    stage_f32<64, 192, 256>(wqkv + ch * (64 * 192), 192, ldsB, tid);
    __syncthreads();
    f32x4 acc[2][4];
    #pragma unroll
    for (int i = 0; i < 2; ++i)
      #pragma unroll
      for (int j = 0; j < 4; ++j)
        #pragma unroll
        for (int e = 0; e < 4; ++e) acc[i][j][e] = 0.f;
    mma_chunk<192, 2, 4, 4>(ldsA, ldsB, lane, wm0, 0, 0, acc);
    u16* dst;
    int pbase = ch * 64;
    if (ch < 3) dst = q;
    else if (ch < 6) { dst = kk; pbase -= 192; }
    else { dst = v; pbase -= 384; }
    #pragma unroll
    for (int j = 0; j < 4; ++j) {
      int pc = pbase + j * 16 + colL;
      float bias = bqkv[ch * 64 + j * 16 + colL];
      #pragma unroll
      for (int i = 0; i < 2; ++i)
        #pragma unroll
        for (int rr = 0; rr < 4; ++rr) {
          int m = blockIdx.x * 128 + wm0 + i * 16 + rq + rr;  // natural row j
          int b = m >> 16, i1 = (m >> 12) & 15, i2 = (m >> 8) & 15, i3 = (m >> 4) & 15,
              i4 = m & 15;
          int w = (((((b << 4) | i1) << 4) | i3) << 8) | (i2 << 4) | i4;
          dst[(size_t)w * 192 + pc] = f2b(acc[i][j][rr] + bias);
        }
    }
  }
}

// ---- K2: fully fused per-window attention: QK^T -> softmax -> P(LDS) -> PV -> o.
// One block = one window (512 thr, 8 waves). LDS phases: {Q 96K | K 48K} then
// {P 128K | Vchunk 16K}. P never touches HBM; V transposed in-LDS from natural v.
__global__ __launch_bounds__(512) void k_fused(const u16* __restrict__ q,
                                               const u16* __restrict__ kk,
                                               const u16* __restrict__ v,
                                               u16* __restrict__ o) {
  __shared__ __align__(16) char lds[147456];
  char* ldsQ = lds;            // [0, 96K)   phase A
  char* ldsK = lds + 98304;    // [96K,144K) phase A
  char* ldsP = lds;            // [0,128K)   phase B (reuses Q/K space)
  char* ldsV = lds + 131072;   // [128K,144K) phase B, 32 c-rows x 512B
  int tid = threadIdx.x, z = blockIdx.x;
  int lane = tid & 63, wid = tid >> 6;
  int wm0 = wid * 32;
  const u16* qb = q + (size_t)z * 49152;
  const u16* kb = kk + (size_t)z * 49152;
  const u16* vb = v + (size_t)z * 49152;
  u16* ob = o + (size_t)z * 49152;

  stage_b16<256, 192, 512>(qb, 192, ldsQ, tid);
  stage_b16<128, 192, 512>(kb, 192, ldsK, tid);
  // reg-prefetch K rows 128..255 (flies during first QK^T half)
  int4 kreg[6];
  #pragma unroll
  for (int s = 0; s < 6; ++s) {
    int ci = tid + s * 512;
    int r = ci / 24, u = ci % 24;
    kreg[s] = *reinterpret_cast<const int4*>(kb + (size_t)(128 + r) * 192 + u * 8);
  }
  f32x4 acc[2][16];
  #pragma unroll
  for (int i = 0; i < 2; ++i)
    #pragma unroll
    for (int j = 0; j < 16; ++j)
      #pragma unroll
      for (int e = 0; e < 4; ++e) acc[i][j][e] = 0.f;
  __syncthreads();
  mma_chunk<192, 2, 8, 16>(ldsQ, ldsK, lane, wm0, 0, 0, acc);
  __syncthreads();
  #pragma unroll
  for (int s = 0; s < 6; ++s) {
    int ci = tid + s * 512;
    int r = ci / 24, u = ci % 24;
    *reinterpret_cast<int4*>(ldsK + r * 384 + ((u * 16) ^ ((r & 7) << 4))) = kreg[s];
  }
  __syncthreads();
  mma_chunk<192, 2, 8, 16>(ldsQ, ldsK, lane, wm0, 0, 8, acc);
  __syncthreads();  // all QK^T LDS reads done; Q/K space now reusable

  // prefetch V chunk 0 (flies during softmax + P writes)
  int4 vreg[2];
  #pragma unroll
  for (int s = 0; s < 2; ++s) {
    int ci = tid + s * 512;
    int tt = ci >> 2, u = ci & 3;
    vreg[s] = *reinterpret_cast<const int4*>(vb + (size_t)tt * 192 + u * 8);
  }

  // in-register row softmax; write bf16 P to LDS (each wave only its own 32 rows,
  // which only it reads back as PV A-fragments -> no cross-wave sync needed)
  const float scale = 0.07216878364870323f;  // 1/sqrt(192)
  int colL = lane & 15, rq = (lane >> 4) * 4;
  #pragma unroll
  for (int i = 0; i < 2; ++i)
    #pragma unroll
    for (int rr = 0; rr < 4; ++rr) {
      float m = -1e30f;
      #pragma unroll
      for (int j = 0; j < 16; ++j) m = fmaxf(m, acc[i][j][rr]);
      #pragma unroll
      for (int off = 8; off; off >>= 1) m = fmaxf(m, __shfl_xor(m, off));
      float s = 0.f;
      #pragma unroll
      for (int j = 0; j < 16; ++j) {
        float e = __expf((acc[i][j][rr] - m) * scale);
        acc[i][j][rr] = e;
        s += e;
      }
      #pragma unroll
      for (int off = 8; off; off >>= 1) s += __shfl_xor(s, off);
      float iv = 1.0f / s;
      int row = wm0 + i * 16 + rq + rr;
      int swz = (row & 7) << 4;
      #pragma unroll
      for (int j = 0; j < 16; ++j) {
        int tc = j * 16 + colL;
        *reinterpret_cast<u16*>(ldsP + row * 512 + ((tc * 2) ^ swz)) =
            f2b(acc[i][j][rr] * iv);
      }
    }

  // PV: 6 chunks of 32 channels; V transposed into LDS; next chunk's global loads
  // issued before this chunk's MFMA (software pipeline)
  #pragma unroll 1
  for (int cc = 0; cc < 6; ++cc) {
    __syncthreads();  // prior chunk's ldsV reads (and, at cc=0, QK^T reads) done
    #pragma unroll
    for (int s = 0; s < 2; ++s) {
      int ci = tid + s * 512;
      int tt = ci >> 2, u = ci & 3;
      unsigned w0 = (unsigned)vreg[s].x, w1 = (unsigned)vreg[s].y,
               w2 = (unsigned)vreg[s].z, w3 = (unsigned)vreg[s].w;
      int tb = tt * 2;
      char* base = ldsV + u * 8 * 512;
      *reinterpret_cast<u16*>(base + 0 * 512 + (tb ^ 0x00)) = (u16)(w0 & 0xFFFF);
      *reinterpret_cast<u16*>(base + 1 * 512 + (tb ^ 0x10)) = (u16)(w0 >> 16);
      *reinterpret_cast<u16*>(base + 2 * 512 + (tb ^ 0x20)) = (u16)(w1 & 0xFFFF);
      *reinterpret_cast<u16*>(base + 3 * 512 + (tb ^ 0x30)) = (u16)(w1 >> 16);
      *reinterpret_cast<u16*>(base + 4 * 512 + (tb ^ 0x40)) = (u16)(w2 & 0xFFFF);
      *reinterpret_cast<u16*>(base + 5 * 512 + (tb ^ 0x50)) = (u16)(w2 >> 16);
      *reinterpret_cast<u16*>(base + 6 * 512 + (tb ^ 0x60)) = (u16)(w3 & 0xFFFF);
      *reinterpret_cast<u16*>(base + 7 * 512 + (tb ^ 0x70)) = (u16)(w3 >> 16);
    }
    if (cc < 5) {
      #pragma unroll
      for (int s = 0; s < 2; ++s) {
        int ci = tid + s * 512;
        int tt = ci >> 2, u = ci & 3;
        vreg[s] =
            *reinterpret_cast<const int4*>(vb + (size_t)tt * 192 + (cc + 1) * 32 + u * 8);
      }
    }
    __syncthreads();
    f32x4 acc2[2][2];
    #pragma unroll
    for (int i = 0; i < 2; ++i)
      #pragma unroll
      for (int j = 0; j < 2; ++j)
        #pragma unroll
        for (int e = 0; e < 4; ++e) acc2[i][j][e] = 0.f;
    mma_chunk<256, 2, 2, 2>(ldsP, ldsV, lane, wm0, 0, 0, acc2);
    #pragma unroll
    for (int i = 0; i < 2; ++i)
      #pragma unroll
      for (int j = 0; j < 2; ++j)
        #pragma unroll
        for (int rr = 0; rr < 4; ++rr) {
          int row = wm0 + i * 16 + rq + rr;
          ob[row * 192 + cc * 32 + j * 16 + colL] = f2b(acc2[i][j][rr]);
        }
  }
}

// ---- K3: lepe (depthwise 3x3 SAME on the reinterpreted [C][16][16] planes), o += lepe.
// REWRITE: one block = 64 independent planes of one window. v staged to LDS
// (plane stride 520B -> ds_read_b64 stencil reads ~4-way, acceptable). Each thread
// owns a 4-row strip of one plane: 6 input rows loaded+converted ONCE into registers
// (all indices compile-time after unroll), 64 outputs, coalesced int4 o RMW.
__global__ __launch_bounds__(256) void k_lepe(const u16* __restrict__ v,
                                              u16* __restrict__ o,
                                              const float* __restrict__ wpe,
                                              const float* __restrict__ bpe) {
  __shared__ __align__(16) char lds[64 * 520];
  int tid = threadIdx.x;
  int g = blockIdx.x, z = blockIdx.y;  // g: plane-group (3 x 64 planes per window)
  const u16* vb = v + (size_t)z * 49152 + g * 16384;
  // stage 64 planes x 512B, fully coalesced global int4 reads
  #pragma unroll
  for (int s = 0; s < 8; ++s) {
    int ci = tid + s * 256;
    int4 vv = *reinterpret_cast<const int4*>(vb + ci * 8);
    char* dst = lds + (ci >> 5) * 520 + (ci & 31) * 16;
    int2 lo, hi;
    lo.x = vv.x; lo.y = vv.y; hi.x = vv.z; hi.y = vv.w;
    *reinterpret_cast<int2*>(dst) = lo;       // 8B-aligned (520 % 8 == 0)
    *reinterpret_cast<int2*>(dst + 8) = hi;
  }
  __syncthreads();
  int p = tid & 63;   // plane within block (lane == plane: 2-lane/bank LDS reads x4)
  int a = tid >> 6;   // row group 0..3 (wave-uniform -> uniform edge branches)
  int cp = g * 64 + p;
  float w[9];
  #pragma unroll
  for (int i = 0; i < 9; ++i) w[i] = wpe[cp * 9 + i];
  float bias = bpe[cp];
  const char* Lp = lds + p * 520;
  // load the 6 needed rows (4a-1 .. 4a+4), zero-padded at plane edges
  float R[6][16];
  #pragma unroll
  for (int rr = 0; rr < 6; ++rr) {
    int row = a * 4 - 1 + rr;
    if (row >= 0 && row < 16) {
      #pragma unroll
      for (int c = 0; c < 4; ++c) {
        uint2 d = *reinterpret_cast<const uint2*>(Lp + row * 32 + c * 8);
        R[rr][c * 4 + 0] = b2f((u16)(d.x & 0xFFFF));
        R[rr][c * 4 + 1] = b2f((u16)(d.x >> 16));
        R[rr][c * 4 + 2] = b2f((u16)(d.y & 0xFFFF));
        R[rr][c * 4 + 3] = b2f((u16)(d.y >> 16));
      }
    } else {
      #pragma unroll
      for (int xx = 0; xx < 16; ++xx) R[rr][xx] = 0.f;
    }
  }
  u16* ob = o + (size_t)z * 49152 + g * 16384 + p * 256 + a * 64;
  #pragma unroll
  for (int rr = 0; rr < 4; ++rr) {
    float accr[16];
    #pragma unroll
    for (int xx = 0; xx < 16; ++xx) {
      float s = bias;
      #pragma unroll
      for (int dy = 0; dy < 3; ++dy) {
        if (xx > 0) s += w[dy * 3 + 0] * R[rr + dy][xx - 1];
        s += w[dy * 3 + 1] * R[rr + dy][xx];
        if (xx < 15) s += w[dy * 3 + 2] * R[rr + dy][xx + 1];
      }
      accr[xx] = s;
    }
    // coalesced-in-L1 o RMW (2 x int4 per row)
    #pragma unroll
    for (int hh = 0; hh < 2; ++hh) {
      int4 ov = *reinterpret_cast<int4*>(ob + rr * 16 + hh * 8);
      unsigned* owp = reinterpret_cast<unsigned*>(&ov);
      #pragma unroll
      for (int c = 0; c < 4; ++c) {
        unsigned word = owp[c];
        float lo = b2f((u16)(word & 0xFFFF)) + accr[hh * 8 + c * 2];
        float hi2 = b2f((u16)(word >> 16)) + accr[hh * 8 + c * 2 + 1];
        owp[c] = (unsigned)f2b(lo) | ((unsigned)f2b(hi2) << 16);
      }
      *reinterpret_cast<int4*>(ob + rr * 16 + hh * 8) = ov;
    }
  }
}

// ---- K4: out = (o @ w_out^T + b_out); o-tile staged ONCE, 3 weight chunks in-block;
// window row w -> natural row j scatter on the f32 store.
__global__ __launch_bounds__(256) void k_outproj(const u16* __restrict__ o,
                                                 const float* __restrict__ wout,
                                                 const float* __restrict__ bout,
                                                 float* __restrict__ out) {
  __shared__ __align__(16) char ldsA[128 * 384];
  __shared__ __align__(16) char ldsB[64 * 384];
  int tid = threadIdx.x;
  stage_b16<128, 192, 256>(o + (size_t)blockIdx.x * (128 * 192), 192, ldsA, tid);
  int lane = tid & 63, wid = tid >> 6;
  int wm0 = wid * 32;
  int colL = lane & 15, rq = (lane >> 4) * 4;
  #pragma unroll 1
  for (int ch = 0; ch < 3; ++ch) {
    if (ch) __syncthreads();
    stage_f32<64, 192, 256>(wout + ch * (64 * 192), 192, ldsB, tid);
    __syncthreads();
    f32x4 acc[2][4];
    #pragma unroll
    for (int i = 0; i < 2; ++i)
      #pragma unroll
      for (int j = 0; j < 4; ++j)
        #pragma unroll
        for (int e = 0; e < 4; ++e) acc[i][j][e] = 0.f;
    mma_chunk<192, 2, 4, 4>(ldsA, ldsB, lane, wm0, 0, 0, acc);
    #pragma unroll
    for (int j = 0; j < 4; ++j) {
      int p = ch * 64 + j * 16 + colL;
      float bias = bout[p];
      #pragma unroll
      for (int i = 0; i < 2; ++i)
        #pragma unroll
        for (int rr = 0; rr < 4; ++rr) {
          int w = blockIdx.x * 128 + wm0 + i * 16 + rq + rr;
          int n = w >> 8, t = w & 255;
          int b = n >> 8, i1 = (n >> 4) & 15, i3 = n & 15, i2 = t >> 4, i4 = t & 15;
          int jj = (((((((b << 4) | i1) << 4) | i2) << 4) | i3) << 4) | i4;
          out[(size_t)jj * 192 + p] = acc[i][j][rr] + bias;
        }
    }
  }
}

extern "C" void kernel_launch(void* const* d_in, const int* in_sizes, int n_in,
                              void* d_out, int out_size, void* d_ws, size_t ws_size,
                              hipStream_t stream) {
  const float* x = (const float*)d_in[0];
  const float* w_qkv = (const float*)d_in[1];
  const float* b_qkv = (const float*)d_in[2];
  const float* w_pe = (const float*)d_in[3];
  const float* b_pe = (const float*)d_in[4];
  const float* w_out = (const float*)d_in[5];
  const float* b_out = (const float*)d_in[6];
  float* out = (float*)d_out;
  char* ws = (char*)d_ws;

  // Workspace (peak 403MB):
  //   q [0,100M) k [100M,201M) v [201M,302M) o [302M,403M)
  u16* q = (u16*)(ws + 0);
  u16* k = (u16*)(ws + 100663296);
  u16* v = (u16*)(ws + 201326592);
  u16* o = (u16*)(ws + 301989888);

  k_qkv<<<dim3(2048), 256, 0, stream>>>(x, w_qkv, b_qkv, q, k, v);
  k_fused<<<dim3(1024), 512, 0, stream>>>(q, k, v, o);
  k_lepe<<<dim3(3, 1024), 256, 0, stream>>>(v, o, w_pe, b_pe);
  k_outproj<<<dim3(2048), 256, 0, stream>>>(o, w_out, b_out, out);
}

// Round 6
// 843.018 us; speedup vs baseline: 1.3515x; 1.0228x over previous
//
#include <hip/hip_runtime.h>

typedef unsigned short u16;
typedef short bf16x8 __attribute__((ext_vector_type(8)));
typedef float f32x4 __attribute__((ext_vector_type(4)));

__device__ __forceinline__ u16 f2b(float f) {
  union { float f; unsigned u; } v; v.f = f;
  unsigned r = v.u + 0x7FFFu + ((v.u >> 16) & 1u);
  return (u16)(r >> 16);
}
__device__ __forceinline__ float b2f(u16 h) {
  union { unsigned u; float f; } v; v.u = ((unsigned)h) << 16;
  return v.f;
}

// ---- LDS staging: R x K bf16 tile, XOR-swizzled (byte ^= (row&7)<<4) so MFMA
// fragment ds_read_b128 at row-stride 2K (384B/512B ≡ bank 0) lands ~2-way (free).
template <int R, int K, int T>
__device__ __forceinline__ void stage_f32(const float* __restrict__ src, int rowStride,
                                          char* lds, int tid) {
  constexpr int CPR = K / 4;
  constexpr int CHUNKS = R * CPR;
  #pragma unroll
  for (int ci = tid; ci < CHUNKS; ci += T) {
    int r = ci / CPR, u = ci % CPR;
    float4 vv = *reinterpret_cast<const float4*>(src + (size_t)r * rowStride + u * 4);
    ushort4 h;
    h.x = f2b(vv.x); h.y = f2b(vv.y); h.z = f2b(vv.z); h.w = f2b(vv.w);
    int bc = (u * 8) ^ ((r & 7) << 4);
    *reinterpret_cast<ushort4*>(lds + r * (2 * K) + bc) = h;
  }
}

template <int R, int K, int T>
__device__ __forceinline__ void stage_b16(const u16* __restrict__ src, int rowStride,
                                          char* lds, int tid) {
  constexpr int CPR = K / 8;
  constexpr int CHUNKS = R * CPR;
  #pragma unroll
  for (int ci = tid; ci < CHUNKS; ci += T) {
    int r = ci / CPR, u = ci % CPR;
    int4 vv = *reinterpret_cast<const int4*>(src + (size_t)r * rowStride + u * 8);
    int bc = (u * 16) ^ ((r & 7) << 4);
    *reinterpret_cast<int4*>(lds + r * (2 * K) + bc) = vv;
  }
}

// ---- MFMA over one staged K-chunk. A [BM][KC], B [BN][KC], row-major bf16
// ([m][k]/[n][k]), XOR swizzle as above. Accumulates into acc[i][jo+j]. jo MUST be a
// compile-time constant at every call site (rule #20: runtime-indexed regs -> scratch).
template <int KC, int FM, int FN, int FNT>
__device__ __forceinline__ void mma_chunk(const char* ldsA, const char* ldsB, int lane,
                                          int wm0, int wn0, int jo, f32x4 (&acc)[FM][FNT]) {
  constexpr int LD = 2 * KC;
  #pragma unroll
  for (int ks = 0; ks < KC / 32; ++ks) {
    bf16x8 a[FM], b[FN];
    int kb = ks * 64 + ((lane >> 4) << 4);
    #pragma unroll
    for (int i = 0; i < FM; ++i) {
      int row = wm0 + i * 16 + (lane & 15);
      a[i] = *reinterpret_cast<const bf16x8*>(ldsA + row * LD + (kb ^ ((row & 7) << 4)));
    }
    #pragma unroll
    for (int j = 0; j < FN; ++j) {
      int row = wn0 + j * 16 + (lane & 15);
      b[j] = *reinterpret_cast<const bf16x8*>(ldsB + row * LD + (kb ^ ((row & 7) << 4)));
    }
    #pragma unroll
    for (int i = 0; i < FM; ++i)
      #pragma unroll
      for (int j = 0; j < FN; ++j)
        acc[i][jo + j] =
            __builtin_amdgcn_mfma_f32_16x16x32_bf16(a[i], b[j], acc[i][jo + j], 0, 0, 0);
  }
}

// ---- K0: f32 -> bf16 weight pre-convert (tiny). 4 elems/thread.
__global__ __launch_bounds__(256) void k_f2b(const float* __restrict__ src,
                                             u16* __restrict__ dst, int n) {
  int i = (blockIdx.x * 256 + threadIdx.x) * 4;
  if (i < n) {
    float4 vv = *reinterpret_cast<const float4*>(src + i);
    ushort4 h;
    h.x = f2b(vv.x); h.y = f2b(vv.y); h.z = f2b(vv.z); h.w = f2b(vv.w);
    *reinterpret_cast<ushort4*>(dst + i) = h;
  }
}

// ---- K1: qkv = x @ w_qkv^T + b_qkv. x-tile staged ONCE (f32->bf16); 9 bf16 weight
// chunks looped in-block with register prefetch (load ch+1 while MFMA ch runs).
// Row-permutation offsets precomputed once. q/k/v bf16 window-major.
__global__ __launch_bounds__(256) void k_qkv(const float* __restrict__ x,
                                             const u16* __restrict__ wb,
                                             const float* __restrict__ bqkv,
                                             u16* __restrict__ q, u16* __restrict__ kk,
                                             u16* __restrict__ v) {
  __shared__ __align__(16) char ldsA[128 * 384];
  __shared__ __align__(16) char ldsB[64 * 384];
  int tid = threadIdx.x;
  stage_f32<128, 192, 256>(x + (size_t)blockIdx.x * (128 * 192), 192, ldsA, tid);
  int lane = tid & 63, wid = tid >> 6;
  int wm0 = wid * 32;
  int colL = lane & 15, rq = (lane >> 4) * 4;
  // precompute natural-row -> window-row byte offsets (reused across all 9 chunks)
  int wrow[8];
  #pragma unroll
  for (int i = 0; i < 2; ++i)
    #pragma unroll
    for (int rr = 0; rr < 4; ++rr) {
      int m = blockIdx.x * 128 + wm0 + i * 16 + rq + rr;  // natural row j
      int b = m >> 16, i1 = (m >> 12) & 15, i2 = (m >> 8) & 15, i3 = (m >> 4) & 15,
          i4 = m & 15;
      int w = (((((b << 4) | i1) << 4) | i3) << 8) | (i2 << 4) | i4;
      wrow[i * 4 + rr] = w * 192;
    }
  // prefetch B chunk 0 into registers (6 int4 / thread)
  int4 breg[6];
  #pragma unroll
  for (int s = 0; s < 6; ++s) {
    int ci = tid + s * 256;
    int r = ci / 24, u = ci % 24;
    breg[s] = *reinterpret_cast<const int4*>(wb + r * 192 + u * 8);
  }
  #pragma unroll 1
  for (int ch = 0; ch < 9; ++ch) {
    if (ch) __syncthreads();  // prev chunk's ldsB reads done
    #pragma unroll
    for (int s = 0; s < 6; ++s) {
      int ci = tid + s * 256;
      int r = ci / 24, u = ci % 24;
      *reinterpret_cast<int4*>(ldsB + r * 384 + ((u * 16) ^ ((r & 7) << 4))) = breg[s];
    }
    if (ch < 8) {
      #pragma unroll
      for (int s = 0; s < 6; ++s) {
        int ci = tid + s * 256;
        int r = ci / 24, u = ci % 24;
        breg[s] =
            *reinterpret_cast<const int4*>(wb + (ch + 1) * 12288 + r * 192 + u * 8);
      }
    }
    __syncthreads();  // ldsB (and, at ch=0, ldsA) visible
    f32x4 acc[2][4];
    #pragma unroll
    for (int i = 0; i < 2; ++i)
      #pragma unroll
      for (int j = 0; j < 4; ++j)
        #pragma unroll
        for (int e = 0; e < 4; ++e) acc[i][j][e] = 0.f;
    mma_chunk<192, 2, 4, 4>(ldsA, ldsB, lane, wm0, 0, 0, acc);
    u16* dst;
    int pbase = ch * 64;
    if (ch < 3) dst = q;
    else if (ch < 6) { dst = kk; pbase -= 192; }
    else { dst = v; pbase -= 384; }
    #pragma unroll
    for (int j = 0; j < 4; ++j) {
      int pc = pbase + j * 16 + colL;
      float bias = bqkv[ch * 64 + j * 16 + colL];
      #pragma unroll
      for (int i = 0; i < 2; ++i)
        #pragma unroll
        for (int rr = 0; rr < 4; ++rr)
          dst[(size_t)(wrow[i * 4 + rr] + pc)] = f2b(acc[i][j][rr] + bias);
    }
  }
}

// ---- K2: fully fused per-window attention: QK^T -> softmax -> P(LDS) -> PV -> o.
// One block = one window (512 thr, 8 waves). LDS phases: {Q 96K | K 48K} then
// {P 128K | Vchunk 16K}. P never touches HBM; V transposed in-LDS from natural v.
__global__ __launch_bounds__(512) void k_fused(const u16* __restrict__ q,
                                               const u16* __restrict__ kk,
                                               const u16* __restrict__ v,
                                               u16* __restrict__ o) {
  __shared__ __align__(16) char lds[147456];
  char* ldsQ = lds;            // [0, 96K)   phase A
  char* ldsK = lds + 98304;    // [96K,144K) phase A
  char* ldsP = lds;            // [0,128K)   phase B (reuses Q/K space)
  char* ldsV = lds + 131072;   // [128K,144K) phase B, 32 c-rows x 512B
  int tid = threadIdx.x, z = blockIdx.x;
  int lane = tid & 63, wid = tid >> 6;
  int wm0 = wid * 32;
  const u16* qb = q + (size_t)z * 49152;
  const u16* kb = kk + (size_t)z * 49152;
  const u16* vb = v + (size_t)z * 49152;
  u16* ob = o + (size_t)z * 49152;

  stage_b16<256, 192, 512>(qb, 192, ldsQ, tid);
  stage_b16<128, 192, 512>(kb, 192, ldsK, tid);
  // reg-prefetch K rows 128..255 (flies during first QK^T half)
  int4 kreg[6];
  #pragma unroll
  for (int s = 0; s < 6; ++s) {
    int ci = tid + s * 512;
    int r = ci / 24, u = ci % 24;
    kreg[s] = *reinterpret_cast<const int4*>(kb + (size_t)(128 + r) * 192 + u * 8);
  }
  f32x4 acc[2][16];
  #pragma unroll
  for (int i = 0; i < 2; ++i)
    #pragma unroll
    for (int j = 0; j < 16; ++j)
      #pragma unroll
      for (int e = 0; e < 4; ++e) acc[i][j][e] = 0.f;
  __syncthreads();
  mma_chunk<192, 2, 8, 16>(ldsQ, ldsK, lane, wm0, 0, 0, acc);
  __syncthreads();
  #pragma unroll
  for (int s = 0; s < 6; ++s) {
    int ci = tid + s * 512;
    int r = ci / 24, u = ci % 24;
    *reinterpret_cast<int4*>(ldsK + r * 384 + ((u * 16) ^ ((r & 7) << 4))) = kreg[s];
  }
  __syncthreads();
  mma_chunk<192, 2, 8, 16>(ldsQ, ldsK, lane, wm0, 0, 8, acc);
  __syncthreads();  // all QK^T LDS reads done; Q/K space now reusable

  // prefetch V chunk 0 (flies during softmax + P writes)
  int4 vreg[2];
  #pragma unroll
  for (int s = 0; s < 2; ++s) {
    int ci = tid + s * 512;
    int tt = ci >> 2, u = ci & 3;
    vreg[s] = *reinterpret_cast<const int4*>(vb + (size_t)tt * 192 + u * 8);
  }

  // in-register row softmax; write bf16 P to LDS (each wave only its own 32 rows,
  // which only it reads back as PV A-fragments -> no cross-wave sync needed)
  const float scale = 0.07216878364870323f;  // 1/sqrt(192)
  int colL = lane & 15, rq = (lane >> 4) * 4;
  #pragma unroll
  for (int i = 0; i < 2; ++i)
    #pragma unroll
    for (int rr = 0; rr < 4; ++rr) {
      float m = -1e30f;
      #pragma unroll
      for (int j = 0; j < 16; ++j) m = fmaxf(m, acc[i][j][rr]);
      #pragma unroll
      for (int off = 8; off; off >>= 1) m = fmaxf(m, __shfl_xor(m, off));
      float s = 0.f;
      #pragma unroll
      for (int j = 0; j < 16; ++j) {
        float e = __expf((acc[i][j][rr] - m) * scale);
        acc[i][j][rr] = e;
        s += e;
      }
      #pragma unroll
      for (int off = 8; off; off >>= 1) s += __shfl_xor(s, off);
      float iv = 1.0f / s;
      int row = wm0 + i * 16 + rq + rr;
      int swz = (row & 7) << 4;
      #pragma unroll
      for (int j = 0; j < 16; ++j) {
        int tc = j * 16 + colL;
        *reinterpret_cast<u16*>(ldsP + row * 512 + ((tc * 2) ^ swz)) =
            f2b(acc[i][j][rr] * iv);
      }
    }

  // PV: 6 chunks of 32 channels; V transposed into LDS; next chunk's global loads
  // issued before this chunk's MFMA (software pipeline)
  #pragma unroll 1
  for (int cc = 0; cc < 6; ++cc) {
    __syncthreads();  // prior chunk's ldsV reads (and, at cc=0, QK^T reads) done
    #pragma unroll
    for (int s = 0; s < 2; ++s) {
      int ci = tid + s * 512;
      int tt = ci >> 2, u = ci & 3;
      unsigned w0 = (unsigned)vreg[s].x, w1 = (unsigned)vreg[s].y,
               w2 = (unsigned)vreg[s].z, w3 = (unsigned)vreg[s].w;
      int tb = tt * 2;
      char* base = ldsV + u * 8 * 512;
      *reinterpret_cast<u16*>(base + 0 * 512 + (tb ^ 0x00)) = (u16)(w0 & 0xFFFF);
      *reinterpret_cast<u16*>(base + 1 * 512 + (tb ^ 0x10)) = (u16)(w0 >> 16);
      *reinterpret_cast<u16*>(base + 2 * 512 + (tb ^ 0x20)) = (u16)(w1 & 0xFFFF);
      *reinterpret_cast<u16*>(base + 3 * 512 + (tb ^ 0x30)) = (u16)(w1 >> 16);
      *reinterpret_cast<u16*>(base + 4 * 512 + (tb ^ 0x40)) = (u16)(w2 & 0xFFFF);
      *reinterpret_cast<u16*>(base + 5 * 512 + (tb ^ 0x50)) = (u16)(w2 >> 16);
      *reinterpret_cast<u16*>(base + 6 * 512 + (tb ^ 0x60)) = (u16)(w3 & 0xFFFF);
      *reinterpret_cast<u16*>(base + 7 * 512 + (tb ^ 0x70)) = (u16)(w3 >> 16);
    }
    if (cc < 5) {
      #pragma unroll
      for (int s = 0; s < 2; ++s) {
        int ci = tid + s * 512;
        int tt = ci >> 2, u = ci & 3;
        vreg[s] =
            *reinterpret_cast<const int4*>(vb + (size_t)tt * 192 + (cc + 1) * 32 + u * 8);
      }
    }
    __syncthreads();
    f32x4 acc2[2][2];
    #pragma unroll
    for (int i = 0; i < 2; ++i)
      #pragma unroll
      for (int j = 0; j < 2; ++j)
        #pragma unroll
        for (int e = 0; e < 4; ++e) acc2[i][j][e] = 0.f;
    mma_chunk<256, 2, 2, 2>(ldsP, ldsV, lane, wm0, 0, 0, acc2);
    #pragma unroll
    for (int i = 0; i < 2; ++i)
      #pragma unroll
      for (int j = 0; j < 2; ++j)
        #pragma unroll
        for (int rr = 0; rr < 4; ++rr) {
          int row = wm0 + i * 16 + rq + rr;
          ob[row * 192 + cc * 32 + j * 16 + colL] = f2b(acc2[i][j][rr]);
        }
  }
}

// ---- K3: lepe (depthwise 3x3 SAME on the reinterpreted [C][16][16] planes), o += lepe.
// One block = 64 independent planes of one window; strip-in-registers stencil.
__global__ __launch_bounds__(256) void k_lepe(const u16* __restrict__ v,
                                              u16* __restrict__ o,
                                              const float* __restrict__ wpe,
                                              const float* __restrict__ bpe) {
  __shared__ __align__(16) char lds[64 * 520];
  int tid = threadIdx.x;
  int g = blockIdx.x, z = blockIdx.y;  // g: plane-group (3 x 64 planes per window)
  const u16* vb = v + (size_t)z * 49152 + g * 16384;
  #pragma unroll
  for (int s = 0; s < 8; ++s) {
    int ci = tid + s * 256;
    int4 vv = *reinterpret_cast<const int4*>(vb + ci * 8);
    char* dst = lds + (ci >> 5) * 520 + (ci & 31) * 16;
    int2 lo, hi;
    lo.x = vv.x; lo.y = vv.y; hi.x = vv.z; hi.y = vv.w;
    *reinterpret_cast<int2*>(dst) = lo;
    *reinterpret_cast<int2*>(dst + 8) = hi;
  }
  __syncthreads();
  int p = tid & 63;
  int a = tid >> 6;
  int cp = g * 64 + p;
  float w[9];
  #pragma unroll
  for (int i = 0; i < 9; ++i) w[i] = wpe[cp * 9 + i];
  float bias = bpe[cp];
  const char* Lp = lds + p * 520;
  float R[6][16];
  #pragma unroll
  for (int rr = 0; rr < 6; ++rr) {
    int row = a * 4 - 1 + rr;
    if (row >= 0 && row < 16) {
      #pragma unroll
      for (int c = 0; c < 4; ++c) {
        uint2 d = *reinterpret_cast<const uint2*>(Lp + row * 32 + c * 8);
        R[rr][c * 4 + 0] = b2f((u16)(d.x & 0xFFFF));
        R[rr][c * 4 + 1] = b2f((u16)(d.x >> 16));
        R[rr][c * 4 + 2] = b2f((u16)(d.y & 0xFFFF));
        R[rr][c * 4 + 3] = b2f((u16)(d.y >> 16));
      }
    } else {
      #pragma unroll
      for (int xx = 0; xx < 16; ++xx) R[rr][xx] = 0.f;
    }
  }
  u16* ob = o + (size_t)z * 49152 + g * 16384 + p * 256 + a * 64;
  #pragma unroll
  for (int rr = 0; rr < 4; ++rr) {
    float accr[16];
    #pragma unroll
    for (int xx = 0; xx < 16; ++xx) {
      float s = bias;
      #pragma unroll
      for (int dy = 0; dy < 3; ++dy) {
        if (xx > 0) s += w[dy * 3 + 0] * R[rr + dy][xx - 1];
        s += w[dy * 3 + 1] * R[rr + dy][xx];
        if (xx < 15) s += w[dy * 3 + 2] * R[rr + dy][xx + 1];
      }
      accr[xx] = s;
    }
    #pragma unroll
    for (int hh = 0; hh < 2; ++hh) {
      int4 ov = *reinterpret_cast<int4*>(ob + rr * 16 + hh * 8);
      unsigned* owp = reinterpret_cast<unsigned*>(&ov);
      #pragma unroll
      for (int c = 0; c < 4; ++c) {
        unsigned word = owp[c];
        float lo = b2f((u16)(word & 0xFFFF)) + accr[hh * 8 + c * 2];
        float hi2 = b2f((u16)(word >> 16)) + accr[hh * 8 + c * 2 + 1];
        owp[c] = (unsigned)f2b(lo) | ((unsigned)f2b(hi2) << 16);
      }
      *reinterpret_cast<int4*>(ob + rr * 16 + hh * 8) = ov;
    }
  }
}

// ---- K4: out = (o @ w_out^T + b_out); o-tile staged ONCE; 3 bf16 weight chunks with
// register prefetch; scatter offsets precomputed once.
__global__ __launch_bounds__(256) void k_outproj(const u16* __restrict__ o,
                                                 const u16* __restrict__ wbo,
                                                 const float* __restrict__ bout,
                                                 float* __restrict__ out) {
  __shared__ __align__(16) char ldsA[128 * 384];
  __shared__ __align__(16) char ldsB[64 * 384];
  int tid = threadIdx.x;
  stage_b16<128, 192, 256>(o + (size_t)blockIdx.x * (128 * 192), 192, ldsA, tid);
  int lane = tid & 63, wid = tid >> 6;
  int wm0 = wid * 32;
  int colL = lane & 15, rq = (lane >> 4) * 4;
  int jjoff[8];
  #pragma unroll
  for (int i = 0; i < 2; ++i)
    #pragma unroll
    for (int rr = 0; rr < 4; ++rr) {
      int w = blockIdx.x * 128 + wm0 + i * 16 + rq + rr;
      int n = w >> 8, t = w & 255;
      int b = n >> 8, i1 = (n >> 4) & 15, i3 = n & 15, i2 = t >> 4, i4 = t & 15;
      int jj = (((((((b << 4) | i1) << 4) | i2) << 4) | i3) << 4) | i4;
      jjoff[i * 4 + rr] = jj * 192;
    }
  int4 breg[6];
  #pragma unroll
  for (int s = 0; s < 6; ++s) {
    int ci = tid + s * 256;
    int r = ci / 24, u = ci % 24;
    breg[s] = *reinterpret_cast<const int4*>(wbo + r * 192 + u * 8);
  }
  #pragma unroll 1
  for (int ch = 0; ch < 3; ++ch) {
    if (ch) __syncthreads();
    #pragma unroll
    for (int s = 0; s < 6; ++s) {
      int ci = tid + s * 256;
      int r = ci / 24, u = ci % 24;
      *reinterpret_cast<int4*>(ldsB + r * 384 + ((u * 16) ^ ((r & 7) << 4))) = breg[s];
    }
    if (ch < 2) {
      #pragma unroll
      for (int s = 0; s < 6; ++s) {
        int ci = tid + s * 256;
        int r = ci / 24, u = ci % 24;
        breg[s] =
            *reinterpret_cast<const int4*>(wbo + (ch + 1) * 12288 + r * 192 + u * 8);
      }
    }
    __syncthreads();
    f32x4 acc[2][4];
    #pragma unroll
    for (int i = 0; i < 2; ++i)
      #pragma unroll
      for (int j = 0; j < 4; ++j)
        #pragma unroll
        for (int e = 0; e < 4; ++e) acc[i][j][e] = 0.f;
    mma_chunk<192, 2, 4, 4>(ldsA, ldsB, lane, wm0, 0, 0, acc);
    #pragma unroll
    for (int j = 0; j < 4; ++j) {
      int p = ch * 64 + j * 16 + colL;
      float bias = bout[p];
      #pragma unroll
      for (int i = 0; i < 2; ++i)
        #pragma unroll
        for (int rr = 0; rr < 4; ++rr)
          out[(size_t)(jjoff[i * 4 + rr] + p)] = acc[i][j][rr] + bias;
    }
  }
}

extern "C" void kernel_launch(void* const* d_in, const int* in_sizes, int n_in,
                              void* d_out, int out_size, void* d_ws, size_t ws_size,
                              hipStream_t stream) {
  const float* x = (const float*)d_in[0];
  const float* w_qkv = (const float*)d_in[1];
  const float* b_qkv = (const float*)d_in[2];
  const float* w_pe = (const float*)d_in[3];
  const float* b_pe = (const float*)d_in[4];
  const float* w_out = (const float*)d_in[5];
  const float* b_out = (const float*)d_in[6];
  float* out = (float*)d_out;
  char* ws = (char*)d_ws;

  // Workspace (peak 384 MiB, unchanged from r4):
  //   q [0,100M) k [100M,201M) v [201M,302M) o [302M,403M)
  // Scratch-in-aliased-memory (no ws growth):
  //   wb  (qkv weights bf16, 221 KB) -> tail of d_out (192 MB f32; fully
  //        rewritten by k_outproj at the end, read only during k_qkv)
  //   wbo (out-proj weights bf16, 74 KB) -> q region, converted AFTER k_fused
  //        (q dead by then), read only by k_outproj
  u16* q = (u16*)(ws + 0);
  u16* k = (u16*)(ws + 100663296);
  u16* v = (u16*)(ws + 201326592);
  u16* o = (u16*)(ws + 301989888);
  u16* wb = (u16*)((char*)d_out + 190000000);  // 221184 B used, well inside 192MB
  u16* wbo = (u16*)(ws + 0);

  k_f2b<<<dim3(108), 256, 0, stream>>>(w_qkv, wb, 110592);
  k_qkv<<<dim3(2048), 256, 0, stream>>>(x, wb, b_qkv, q, k, v);
  k_fused<<<dim3(1024), 512, 0, stream>>>(q, k, v, o);
  k_f2b<<<dim3(36), 256, 0, stream>>>(w_out, wbo, 36864);
  k_lepe<<<dim3(3, 1024), 256, 0, stream>>>(v, o, w_pe, b_pe);
  k_outproj<<<dim3(2048), 256, 0, stream>>>(o, wbo, b_out, out);
}